// Round 1
// baseline (217.329 us; speedup 1.0000x reference)
//
#include <hip/hip_runtime.h>
#include <hip/hip_bf16.h>

#define D_DIM 768
#define HS 64
#define SEQ 4096
#define NBATCH 8

typedef short bf8 __attribute__((ext_vector_type(8)));   // 8 bf16 (4 VGPR) MFMA A/B frag
typedef short bf4 __attribute__((ext_vector_type(4)));   // 4 bf16 (8 B)
typedef float f4 __attribute__((ext_vector_type(4)));    // MFMA C/D frag

static __device__ __forceinline__ short f2b(float x) {
    __hip_bfloat16 h = __float2bfloat16(x);
    return __builtin_bit_cast(short, h);
}
// pack two fp32 -> bf16x2 dword (round-half-up): 2 add + 1 v_perm
static __device__ __forceinline__ unsigned pk2(float x, float y) {
    unsigned ux = __builtin_bit_cast(unsigned, x) + 0x8000u;
    unsigned uy = __builtin_bit_cast(unsigned, y) + 0x8000u;
    return __builtin_amdgcn_perm(uy, ux, 0x07060302u);  // {uy[3],uy[2],ux[3],ux[2]}
}

#if defined(__has_builtin)
#if __has_builtin(__builtin_amdgcn_exp2f)
#define EXP2F(x) __builtin_amdgcn_exp2f(x)
#endif
#endif
#ifndef EXP2F
#define EXP2F(x) exp2f(x)
#endif

// ---------------------------------------------------------------------------
// Kernel 0: W[768][64] fp32 x3 -> wt3 in MFMA-fragment-direct order:
//   wt3[(c32*192 + col)*32 + quad*8 + e] = W[k][n],  col = mat*64+n,
//   k = c32*32 + quad*8 + e.  A proj B-frag load is one contiguous 1 KB
//   global_load_dwordx4 per wave. Softmax scale*log2(e) baked into Wq.
// ---------------------------------------------------------------------------
__global__ __launch_bounds__(256) void wconv_kernel(
    const float* __restrict__ Wk, const float* __restrict__ Wq,
    const float* __restrict__ Wv, short* __restrict__ wt3)
{
    int tid = blockIdx.x * 256 + threadIdx.x;
    int mat = tid / (D_DIM * HS);
    int rem = tid - mat * (D_DIM * HS);
    int k = rem >> 6;
    int n = rem & 63;
    const float* W = (mat == 0) ? Wk : (mat == 1) ? Wq : Wv;
    float scale = (mat == 1) ? 0.18033688011112042f : 1.0f;  // log2(e)/8
    int cc = mat * HS + n;
    int c = k >> 5, q = (k >> 3) & 3, e = k & 7;
    wt3[(c * 192 + cc) * 32 + q * 8 + e] = f2b(W[rem] * scale);
}

// ---------------------------------------------------------------------------
// Kernel 1: projections. [32768 x 768] @ [768 x 192] -> q,k,v bf16 [B*S][64].
// 1024 blocks x 256 thr; block = 32-row M-tile, wave = 48 cols.
// R6: write_ix packs fp32->bf16 via pk2 (3 VALU / 2 elems) instead of 16x
// __float2bfloat16 (~5-6 VALU each, RNE+NaN path) — staging was the
// VALU-heavy side of the loop; rounding diff <=1 ulp bf16.
// ---------------------------------------------------------------------------
__global__ __launch_bounds__(256, 3) void proj_kernel(
    const float* __restrict__ ix, const short* __restrict__ wt3,
    short* __restrict__ qg, short* __restrict__ kg, short* __restrict__ vg)
{
    __shared__ short ixl[2][32 * 72];   // [row][k 0..64), stride 72

    const int t = threadIdx.x;
    const int wave = t >> 6, lane = t & 63;
    const int m = lane & 15, quad = lane >> 4;
    const int m0 = blockIdx.x * 32;

    const int srow = t >> 3;          // ix staging: row 0..31
    const int skoff = (t & 7) * 8;    // float col 0,8,..,56

    f4 xr0, xr1;
    auto load_ix = [&](int c) {
        const float* px = ix + (m0 + srow) * D_DIM + c * 64 + skoff;
        xr0 = *(const f4*)px;
        xr1 = *(const f4*)(px + 4);
    };
    auto write_ix = [&](int p) {
        uint4 xw;
        xw.x = pk2(xr0[0], xr0[1]);
        xw.y = pk2(xr0[2], xr0[3]);
        xw.z = pk2(xr1[0], xr1[1]);
        xw.w = pk2(xr1[2], xr1[3]);
        *(uint4*)(&ixl[p][srow * 72 + skoff]) = xw;
    };

    const int colb = wave * 48;
    const short* wbase = wt3 + (colb + m) * 32 + quad * 8;

    bf8 wb[2][2][3];   // [buf][k-half][nt] — register dbuf for B-frags
    auto load_w = [&](int c, int buf) {
        #pragma unroll
        for (int nt = 0; nt < 3; ++nt) {
            const short* pw = wbase + ((size_t)(2 * c) * 192 + nt * 16) * 32;
            wb[buf][0][nt] = *(const bf8*)pw;
            wb[buf][1][nt] = *(const bf8*)(pw + 192 * 32);
        }
    };

    f4 acc[2][3] = {};

    load_ix(0); load_w(0, 0); write_ix(0); __syncthreads();

    #pragma unroll
    for (int c = 0; c < 12; ++c) {      // 64-k chunks
        const int p = c & 1;
        if (c + 1 < 12) { load_ix(c + 1); load_w(c + 1, (c + 1) & 1); }

        bf8 a0 = *(const bf8*)(&ixl[p][m * 72 + quad * 8]);
        bf8 a1 = *(const bf8*)(&ixl[p][m * 72 + 32 + quad * 8]);
        bf8 a2 = *(const bf8*)(&ixl[p][(16 + m) * 72 + quad * 8]);
        bf8 a3 = *(const bf8*)(&ixl[p][(16 + m) * 72 + 32 + quad * 8]);

        #pragma unroll
        for (int nt = 0; nt < 3; ++nt) {
            acc[0][nt] = __builtin_amdgcn_mfma_f32_16x16x32_bf16(a0, wb[p][0][nt], acc[0][nt], 0, 0, 0);
            acc[0][nt] = __builtin_amdgcn_mfma_f32_16x16x32_bf16(a1, wb[p][1][nt], acc[0][nt], 0, 0, 0);
            acc[1][nt] = __builtin_amdgcn_mfma_f32_16x16x32_bf16(a2, wb[p][0][nt], acc[1][nt], 0, 0, 0);
            acc[1][nt] = __builtin_amdgcn_mfma_f32_16x16x32_bf16(a3, wb[p][1][nt], acc[1][nt], 0, 0, 0);
        }

        if (c + 1 < 12) { write_ix((c + 1) & 1); __syncthreads(); }
    }

    // epilogue: C/D frag row = quad*4+r (ix row), col = lane&15 (wt col)
    #pragma unroll
    for (int mt = 0; mt < 2; ++mt) {
        const int row = m0 + mt * 16 + quad * 4;
        #pragma unroll
        for (int nt = 0; nt < 3; ++nt) {
            const int cb = colb + nt * 16;
            short* op = (cb < 64) ? kg : (cb < 128) ? qg : vg;  // d_in order: Wk,Wq,Wv
            const int n = (cb & 63) + m;
            #pragma unroll
            for (int r = 0; r < 4; ++r)
                op[(row + r) * HS + n] = f2b(acc[mt][nt][r]);
        }
    }
}

// ---------------------------------------------------------------------------
// Kernel 2: fused attention, 4-way key split. 64 queries/WAVE (nq=4),
// block = 256 queries, grid 512 = 2 blocks/CU.
// R6 changes (VALU-pipe was ~2.4x MFMA-pipe per chunk — it is the binding
// resource at 2 waves/SIMD):
//  (a) den via ones-MFMA: mfma(ones, pf, dacc) row-sums P on the MFMA pipe
//      (+8 MFMA/chunk) replacing 64 VALU adds/chunk/lane; every lane then
//      holds the full den for its column -> epilogue shfl pair gone, and
//      num/den now use identical bf16-rounded P (consistent rounding).
//  (b) T5 s_setprio(1) around the per-chunk compute cluster (2 async
//      blocks/CU = phase diversity; m191 regime, +4-7%).
// LDS (double-buffered):
//   kl[j][d] stride 72: K rows, A-frags for S^T = K.Q^T (16x16x32).
//   vl: V^T, XOR-swizzled 16B chunks (conflict-free b128 reads).
// pf trick: concat of the two 16-row S^T C-frags post exp+pack is per-lane a
// valid 16x16x32 B-frag under row-perm pi; vl's column encoding bakes pi in.
// ---------------------------------------------------------------------------
__global__ __launch_bounds__(256, 2) void attn_kernel(
    const short* __restrict__ qg, const short* __restrict__ kg,
    const short* __restrict__ vg, float* __restrict__ num0,
    float* __restrict__ num1, float* __restrict__ num2,
    float* __restrict__ num3, float* __restrict__ den0,
    float* __restrict__ den1, float* __restrict__ den2,
    float* __restrict__ den3)
{
    __shared__ short kl[2][64 * 72];
    __shared__ short vl[2][64 * 64];

    const int t = threadIdx.x;
    const int wave = t >> 6, lane = t & 63;
    const int m = lane & 15, quad = lane >> 4;

    // XCD-aware remap: batch = XCD index (512 blocks, 64 per XCD)
    const int flat = blockIdx.x;
    const int lg = (flat & 7) * 64 + (flat >> 3);
    const int qx = lg & 15;
    const int ks = (lg >> 4) & 3;
    const int b  = lg >> 6;

    const int rbase = b * SEQ;
    const int kbase = rbase + ks * (SEQ / 4);
    const int qw = qx * 256 + wave * 64;

    float* __restrict__ nump = (ks == 0) ? num0 : (ks == 1) ? num1 : (ks == 2) ? num2 : num3;
    float* __restrict__ denp = (ks == 0) ? den0 : (ks == 1) ? den1 : (ks == 2) ? den2 : den3;

    // persistent Q B-frags: lane n=q=lane&15, k=d=quad*8+e (+32 per step)
    bf8 qf[4][2];
    #pragma unroll
    for (int nq = 0; nq < 4; ++nq)
        #pragma unroll
        for (int st = 0; st < 2; ++st)
            qf[nq][st] = *(const bf8*)(qg + (rbase + qw + nq * 16 + m) * HS + st * 32 + quad * 8);

    // all-ones A-frag for the den row-sum MFMA (bf16 1.0 = 0x3F80)
    bf8 ones;
    #pragma unroll
    for (int i = 0; i < 8; ++i) ones[i] = (short)0x3F80;

    // K staging: row srow, 32B of d per thread
    const int srow = t >> 2, soff = (t & 3) * 16;
    // V staging: row-pair j0 = 2*jp, 8 d's per thread
    const int jp = t >> 3, dg = t & 7;
    const int j0 = jp * 2;
    const int jj = j0 & 31;
    const int gj = j0 >> 5;
    const int vq = (jj >> 2) & 3;
    const int vh = (jj >> 4) & 1;
    const int vb = (jj & 3) >> 1;
    const int vcol_base = vh * 4 + 2 * vb;
    const int vchunk_l = 4 * gj + vq;

    uint4 kr0, kr1, vr0, vr1;
    auto load_chunk = [&](int c) {
        const short* pk = kg + (kbase + c * 64 + srow) * HS + soff;
        kr0 = *(const uint4*)pk; kr1 = *(const uint4*)(pk + 8);
        const short* pv = vg + (kbase + c * 64 + j0) * HS + dg * 8;
        vr0 = *(const uint4*)pv; vr1 = *(const uint4*)(pv + HS);
    };
    auto write_chunk = [&](int p) {
        *(bf8*)(&kl[p][srow * 72 + soff])     = __builtin_bit_cast(bf8, kr0);
        *(bf8*)(&kl[p][srow * 72 + soff + 8]) = __builtin_bit_cast(bf8, kr1);
        bf8 v0 = __builtin_bit_cast(bf8, vr0), v1 = __builtin_bit_cast(bf8, vr1);
        #pragma unroll
        for (int i = 0; i < 8; ++i) {
            const int d = dg * 8 + i;
            const int chunk = vchunk_l ^ (i ^ dg);     // (d&7)^(d>>3)
            unsigned val = (unsigned short)v0[i] | ((unsigned)(unsigned short)v1[i] << 16);
            *(unsigned*)(&vl[p][d * 64 + chunk * 8 + vcol_base]) = val;
        }
    };

    f4 o[4][4] = {};
    f4 dacc[4] = {};

    load_chunk(0); write_chunk(0); __syncthreads();

    const int NCH = SEQ / 4 / 64;   // 16 chunks of 64 keys
    for (int c = 0; c < NCH; ++c) {
        const int p = c & 1;
        if (c + 1 < NCH) load_chunk(c + 1);

        __builtin_amdgcn_s_setprio(1);
        #pragma unroll
        for (int g = 0; g < 2; ++g) {
            bf8 kA0 = *(const bf8*)(&kl[p][(g * 32 + m) * 72 + quad * 8]);
            bf8 kA1 = *(const bf8*)(&kl[p][(g * 32 + m) * 72 + 32 + quad * 8]);
            bf8 kB0 = *(const bf8*)(&kl[p][(g * 32 + 16 + m) * 72 + quad * 8]);
            bf8 kB1 = *(const bf8*)(&kl[p][(g * 32 + 16 + m) * 72 + 32 + quad * 8]);

            bf8 vf[4];
            #pragma unroll
            for (int dt = 0; dt < 4; ++dt) {
                const int row = dt * 16 + m;
                const int key = (m & 7) ^ (2 * dt + (m >> 3));
                const int chunk = (g * 4 + quad) ^ key;
                vf[dt] = *(const bf8*)(&vl[p][row * 64 + chunk * 8]);
            }

            #pragma unroll
            for (int nq = 0; nq < 4; ++nq) {
                f4 sa = {0.f, 0.f, 0.f, 0.f}, sb = {0.f, 0.f, 0.f, 0.f};
                sa = __builtin_amdgcn_mfma_f32_16x16x32_bf16(kA0, qf[nq][0], sa, 0, 0, 0);
                sa = __builtin_amdgcn_mfma_f32_16x16x32_bf16(kA1, qf[nq][1], sa, 0, 0, 0);
                sb = __builtin_amdgcn_mfma_f32_16x16x32_bf16(kB0, qf[nq][0], sb, 0, 0, 0);
                sb = __builtin_amdgcn_mfma_f32_16x16x32_bf16(kB1, qf[nq][1], sb, 0, 0, 0);
                float e0 = EXP2F(sa[0]), e1 = EXP2F(sa[1]), e2 = EXP2F(sa[2]), e3 = EXP2F(sa[3]);
                float e4 = EXP2F(sb[0]), e5 = EXP2F(sb[1]), e6 = EXP2F(sb[2]), e7 = EXP2F(sb[3]);
                uint4 pu;
                pu.x = pk2(e0, e1); pu.y = pk2(e2, e3);
                pu.z = pk2(e4, e5); pu.w = pk2(e6, e7);
                bf8 pf = __builtin_bit_cast(bf8, pu);
                dacc[nq] = __builtin_amdgcn_mfma_f32_16x16x32_bf16(ones, pf, dacc[nq], 0, 0, 0);
                #pragma unroll
                for (int dt = 0; dt < 4; ++dt)
                    o[nq][dt] = __builtin_amdgcn_mfma_f32_16x16x32_bf16(vf[dt], pf, o[nq][dt], 0, 0, 0);
            }
        }
        __builtin_amdgcn_s_setprio(0);

        if (c + 1 < NCH) { write_chunk((c + 1) & 1); __syncthreads(); }
    }

    // epilogue: O^T frag row=d=dt*16+quad*4+r, col=q=lane&15. Partial sums out.
    // dacc rows are all identical (ones-product), so every lane already holds
    // the full per-split den for its column q — no cross-lane reduce needed.
    #pragma unroll
    for (int nq = 0; nq < 4; ++nq) {
        const int orow = rbase + qw + nq * 16 + m;
        if (quad == 0) denp[orow] = dacc[nq][0];
        #pragma unroll
        for (int dt = 0; dt < 4; ++dt)
            *(f4*)(nump + orow * HS + dt * 16 + quad * 4) = o[nq][dt];
    }
}

// ---------------------------------------------------------------------------
// Kernel 3: combine the four key-splits: out = sum(num_i)/sum(den_i).
// ---------------------------------------------------------------------------
__global__ __launch_bounds__(256) void reduce_kernel(
    float* __restrict__ out, const float* __restrict__ num1,
    const float* __restrict__ num2, const float* __restrict__ num3,
    const float* __restrict__ den0, const float* __restrict__ den1,
    const float* __restrict__ den2, const float* __restrict__ den3)
{
    const int gid = blockIdx.x * 256 + threadIdx.x;
    const int base = gid * 4;
    const int r = base >> 6;
    f4 n0 = *(const f4*)(out + base);
    f4 n1 = *(const f4*)(num1 + base);
    f4 n2 = *(const f4*)(num2 + base);
    f4 n3 = *(const f4*)(num3 + base);
    const float rs = 1.0f / ((den0[r] + den1[r]) + (den2[r] + den3[r]));
    f4 res;
    #pragma unroll
    for (int i = 0; i < 4; ++i) res[i] = ((n0[i] + n1[i]) + (n2[i] + n3[i])) * rs;
    *(f4*)(out + base) = res;
}

extern "C" void kernel_launch(void* const* d_in, const int* in_sizes, int n_in,
                              void* d_out, int out_size, void* d_ws, size_t ws_size,
                              hipStream_t stream) {
    const float* ix = (const float*)d_in[0];
    const float* Wk = (const float*)d_in[1];
    const float* Wq = (const float*)d_in[2];
    const float* Wv = (const float*)d_in[3];
    float* out = (float*)d_out;

    const size_t NQKV = (size_t)NBATCH * SEQ * HS;      // 2,097,152 elements
    short* qg = (short*)d_ws;
    short* kg = qg + NQKV;
    short* vg = kg + NQKV;
    short* wt3 = vg + NQKV;                             // 24*192*32 = 147456 shorts
    char*  fbase = (char*)(wt3 + 24 * 192 * 32);        // 16B-aligned
    float* num1 = (float*)fbase;
    float* num2 = num1 + NQKV;
    float* num3 = num2 + NQKV;
    float* den0 = num3 + NQKV;
    float* den1 = den0 + (size_t)NBATCH * SEQ;
    float* den2 = den1 + (size_t)NBATCH * SEQ;
    float* den3 = den2 + (size_t)NBATCH * SEQ;

    wconv_kernel<<<(3 * D_DIM * HS) / 256, 256, 0, stream>>>(Wk, Wq, Wv, wt3);
    proj_kernel<<<(NBATCH * SEQ) / 32, 256, 0, stream>>>(ix, wt3, qg, kg, vg);
    attn_kernel<<<512, 256, 0, stream>>>(qg, kg, vg, out, num1, num2, num3,
                                         den0, den1, den2, den3);
    reduce_kernel<<<(int)(NQKV / (256 * 4)), 256, 0, stream>>>(
        out, num1, num2, num3, den0, den1, den2, den3);
}

// Round 2
// 216.466 us; speedup vs baseline: 1.0040x; 1.0040x over previous
//
#include <hip/hip_runtime.h>
#include <hip/hip_bf16.h>

#define D_DIM 768
#define HS 64
#define SEQ 4096
#define NBATCH 8

typedef short bf8 __attribute__((ext_vector_type(8)));   // 8 bf16 (4 VGPR) MFMA A/B frag
typedef short bf4 __attribute__((ext_vector_type(4)));   // 4 bf16 (8 B)
typedef float f4 __attribute__((ext_vector_type(4)));    // MFMA C/D frag

static __device__ __forceinline__ short f2b(float x) {
    __hip_bfloat16 h = __float2bfloat16(x);
    return __builtin_bit_cast(short, h);
}
// pack two fp32 -> bf16x2 dword (round-half-up): 2 add + 1 v_perm
static __device__ __forceinline__ unsigned pk2(float x, float y) {
    unsigned ux = __builtin_bit_cast(unsigned, x) + 0x8000u;
    unsigned uy = __builtin_bit_cast(unsigned, y) + 0x8000u;
    return __builtin_amdgcn_perm(uy, ux, 0x07060302u);  // {uy[3],uy[2],ux[3],ux[2]}
}

#if defined(__has_builtin)
#if __has_builtin(__builtin_amdgcn_exp2f)
#define EXP2F(x) __builtin_amdgcn_exp2f(x)
#endif
#endif
#ifndef EXP2F
#define EXP2F(x) exp2f(x)
#endif

// ---------------------------------------------------------------------------
// Kernel 0: W[768][64] fp32 x3 -> wt3 in MFMA-fragment-direct order:
//   wt3[(c32*192 + col)*32 + quad*8 + e] = W[k][n],  col = mat*64+n,
//   k = c32*32 + quad*8 + e.  A proj B-frag load is one contiguous 1 KB
//   global_load_dwordx4 per wave. Softmax scale*log2(e) baked into Wq.
// ---------------------------------------------------------------------------
__global__ __launch_bounds__(256) void wconv_kernel(
    const float* __restrict__ Wk, const float* __restrict__ Wq,
    const float* __restrict__ Wv, short* __restrict__ wt3)
{
    int tid = blockIdx.x * 256 + threadIdx.x;
    int mat = tid / (D_DIM * HS);
    int rem = tid - mat * (D_DIM * HS);
    int k = rem >> 6;
    int n = rem & 63;
    const float* W = (mat == 0) ? Wk : (mat == 1) ? Wq : Wv;
    float scale = (mat == 1) ? 0.18033688011112042f : 1.0f;  // log2(e)/8
    int cc = mat * HS + n;
    int c = k >> 5, q = (k >> 3) & 3, e = k & 7;
    wt3[(c * 192 + cc) * 32 + q * 8 + e] = f2b(W[rem] * scale);
}

// ---------------------------------------------------------------------------
// Kernel 1: projections. [32768 x 768] @ [768 x 192] -> q,k,v bf16 [B*S][64].
// 1024 blocks x 256 thr; block = 32-row M-tile, wave = 48 cols.
// R7: ix staging is 2-chunk-deep register lookahead (sets A/B; chunk x ->
// set x&1). write_ix(c+1) now consumes loads issued at chunk c-1 (~2000 cy
// of cover) instead of the same chunk (~60 cy) — removes the per-chunk
// ~240+ cy vmcnt drain. load_w moved after the MFMA block: reuses wb[p]
// just after its last read, giving its loads 2 chunks of latency cover
// with zero extra registers.
// ---------------------------------------------------------------------------
__global__ __launch_bounds__(256, 3) void proj_kernel(
    const float* __restrict__ ix, const short* __restrict__ wt3,
    short* __restrict__ qg, short* __restrict__ kg, short* __restrict__ vg)
{
    __shared__ short ixl[2][32 * 72];   // [row][k 0..64), stride 72

    const int t = threadIdx.x;
    const int wave = t >> 6, lane = t & 63;
    const int m = lane & 15, quad = lane >> 4;
    const int m0 = blockIdx.x * 32;

    const int srow = t >> 3;          // ix staging: row 0..31
    const int skoff = (t & 7) * 8;    // float col 0,8,..,56

    f4 xa0, xa1, xb0, xb1;            // 2-deep ix lookahead (A=even, B=odd)
    auto load_ix = [&](int c, f4& r0, f4& r1) {
        const float* px = ix + (m0 + srow) * D_DIM + c * 64 + skoff;
        r0 = *(const f4*)px;
        r1 = *(const f4*)(px + 4);
    };
    auto write_ix = [&](int p, f4 r0, f4 r1) {
        uint4 xw;
        xw.x = pk2(r0[0], r0[1]);
        xw.y = pk2(r0[2], r0[3]);
        xw.z = pk2(r1[0], r1[1]);
        xw.w = pk2(r1[2], r1[3]);
        *(uint4*)(&ixl[p][srow * 72 + skoff]) = xw;
    };

    const int colb = wave * 48;
    const short* wbase = wt3 + (colb + m) * 32 + quad * 8;

    bf8 wb[2][2][3];   // [buf][k-half][nt] — register dbuf for B-frags
    auto load_w = [&](int c, int buf) {
        #pragma unroll
        for (int nt = 0; nt < 3; ++nt) {
            const short* pw = wbase + ((size_t)(2 * c) * 192 + nt * 16) * 32;
            wb[buf][0][nt] = *(const bf8*)pw;
            wb[buf][1][nt] = *(const bf8*)(pw + 192 * 32);
        }
    };

    f4 acc[2][3] = {};

    load_ix(0, xa0, xa1);
    load_w(0, 0);
    write_ix(0, xa0, xa1);            // one-time prologue drain
    load_ix(1, xb0, xb1);
    load_w(1, 1);
    __syncthreads();

    auto mfma_block = [&](int p) {
        bf8 a0 = *(const bf8*)(&ixl[p][m * 72 + quad * 8]);
        bf8 a1 = *(const bf8*)(&ixl[p][m * 72 + 32 + quad * 8]);
        bf8 a2 = *(const bf8*)(&ixl[p][(16 + m) * 72 + quad * 8]);
        bf8 a3 = *(const bf8*)(&ixl[p][(16 + m) * 72 + 32 + quad * 8]);
        #pragma unroll
        for (int nt = 0; nt < 3; ++nt) {
            acc[0][nt] = __builtin_amdgcn_mfma_f32_16x16x32_bf16(a0, wb[p][0][nt], acc[0][nt], 0, 0, 0);
            acc[0][nt] = __builtin_amdgcn_mfma_f32_16x16x32_bf16(a1, wb[p][1][nt], acc[0][nt], 0, 0, 0);
            acc[1][nt] = __builtin_amdgcn_mfma_f32_16x16x32_bf16(a2, wb[p][0][nt], acc[1][nt], 0, 0, 0);
            acc[1][nt] = __builtin_amdgcn_mfma_f32_16x16x32_bf16(a3, wb[p][1][nt], acc[1][nt], 0, 0, 0);
        }
    };

    for (int cc = 0; cc < 12; cc += 2) {
        {   // c = cc (even), p = 0: load -> set A, write chunk c+1 from set B
            const int c = cc;
            if (c + 2 < 12) load_ix(c + 2, xa0, xa1);
            mfma_block(0);
            if (c + 2 < 12) load_w(c + 2, 0);
            if (c + 1 < 12) { write_ix(1, xb0, xb1); __syncthreads(); }
        }
        {   // c = cc+1 (odd), p = 1: load -> set B, write chunk c+1 from set A
            const int c = cc + 1;
            if (c + 2 < 12) load_ix(c + 2, xb0, xb1);
            mfma_block(1);
            if (c + 2 < 12) load_w(c + 2, 1);
            if (c + 1 < 12) { write_ix(0, xa0, xa1); __syncthreads(); }
        }
    }

    // epilogue: C/D frag row = quad*4+r (ix row), col = lane&15 (wt col)
    #pragma unroll
    for (int mt = 0; mt < 2; ++mt) {
        const int row = m0 + mt * 16 + quad * 4;
        #pragma unroll
        for (int nt = 0; nt < 3; ++nt) {
            const int cb = colb + nt * 16;
            short* op = (cb < 64) ? kg : (cb < 128) ? qg : vg;  // d_in order: Wk,Wq,Wv
            const int n = (cb & 63) + m;
            #pragma unroll
            for (int r = 0; r < 4; ++r)
                op[(row + r) * HS + n] = f2b(acc[mt][nt][r]);
        }
    }
}

// ---------------------------------------------------------------------------
// Kernel 2: fused attention, 4-way key split. 64 queries/WAVE (nq=4),
// block = 256 queries, grid 512 = 2 blocks/CU.
// R7 (latency-structure round; R6's VALU relief was null -> not VALU-bound):
//  (a) 2-deep global lookahead (reg sets A/B, chunk x -> set x&1): the
//      pre-barrier LDS write consumes loads issued a FULL chunk earlier,
//      so its vmcnt is guaranteed satisfied (T4-lite; compiler emits the
//      counted vmcnt from register deps). +16 VGPR, still <=256.
//  (b) write_chunk hoisted between g=0 and g=1: buffer p^1 was last read
//      in chunk c-1 (ordered by that chunk's barrier), so mid-chunk writes
//      are race-free; the write no longer sits serially between the last
//      MFMA and the barrier.
// LDS (double-buffered):
//   kl[j][d] stride 72: K rows, A-frags for S^T = K.Q^T (16x16x32).
//   vl: V^T, XOR-swizzled 16B chunks (conflict-free b128 reads).
// pf trick: concat of the two 16-row S^T C-frags post exp+pack is per-lane a
// valid 16x16x32 B-frag under row-perm pi; vl's column encoding bakes pi in.
// ---------------------------------------------------------------------------
__global__ __launch_bounds__(256, 2) void attn_kernel(
    const short* __restrict__ qg, const short* __restrict__ kg,
    const short* __restrict__ vg, float* __restrict__ num0,
    float* __restrict__ num1, float* __restrict__ num2,
    float* __restrict__ num3, float* __restrict__ den0,
    float* __restrict__ den1, float* __restrict__ den2,
    float* __restrict__ den3)
{
    __shared__ short kl[2][64 * 72];
    __shared__ short vl[2][64 * 64];

    const int t = threadIdx.x;
    const int wave = t >> 6, lane = t & 63;
    const int m = lane & 15, quad = lane >> 4;

    // XCD-aware remap: batch = XCD index (512 blocks, 64 per XCD)
    const int flat = blockIdx.x;
    const int lg = (flat & 7) * 64 + (flat >> 3);
    const int qx = lg & 15;
    const int ks = (lg >> 4) & 3;
    const int b  = lg >> 6;

    const int rbase = b * SEQ;
    const int kbase = rbase + ks * (SEQ / 4);
    const int qw = qx * 256 + wave * 64;

    float* __restrict__ nump = (ks == 0) ? num0 : (ks == 1) ? num1 : (ks == 2) ? num2 : num3;
    float* __restrict__ denp = (ks == 0) ? den0 : (ks == 1) ? den1 : (ks == 2) ? den2 : den3;

    // K staging: row srow, 32B of d per thread
    const int srow = t >> 2, soff = (t & 3) * 16;
    // V staging: row-pair j0 = 2*jp, 8 d's per thread
    const int jp = t >> 3, dg = t & 7;
    const int j0 = jp * 2;
    const int jj = j0 & 31;
    const int gj = j0 >> 5;
    const int vq = (jj >> 2) & 3;
    const int vh = (jj >> 4) & 1;
    const int vb = (jj & 3) >> 1;
    const int vcol_base = vh * 4 + 2 * vb;
    const int vchunk_l = 4 * gj + vq;

    // 2-deep lookahead register sets: A = even chunks, B = odd chunks
    uint4 kA0r, kA1r, vA0r, vA1r;
    uint4 kB0r, kB1r, vB0r, vB1r;
    auto load_chunk = [&](int c, uint4& k0, uint4& k1, uint4& v0, uint4& v1) {
        const short* pk = kg + (kbase + c * 64 + srow) * HS + soff;
        k0 = *(const uint4*)pk; k1 = *(const uint4*)(pk + 8);
        const short* pv = vg + (kbase + c * 64 + j0) * HS + dg * 8;
        v0 = *(const uint4*)pv; v1 = *(const uint4*)(pv + HS);
    };
    auto write_chunk = [&](int p, uint4 k0, uint4 k1, uint4 v0r, uint4 v1r) {
        *(bf8*)(&kl[p][srow * 72 + soff])     = __builtin_bit_cast(bf8, k0);
        *(bf8*)(&kl[p][srow * 72 + soff + 8]) = __builtin_bit_cast(bf8, k1);
        bf8 v0 = __builtin_bit_cast(bf8, v0r), v1 = __builtin_bit_cast(bf8, v1r);
        #pragma unroll
        for (int i = 0; i < 8; ++i) {
            const int d = dg * 8 + i;
            const int chunk = vchunk_l ^ (i ^ dg);     // (d&7)^(d>>3)
            unsigned val = (unsigned short)v0[i] | ((unsigned)(unsigned short)v1[i] << 16);
            *(unsigned*)(&vl[p][d * 64 + chunk * 8 + vcol_base]) = val;
        }
    };

    f4 o[4][4] = {};
    f4 dacc[4] = {};

    // all-ones A-frag for the den row-sum MFMA (bf16 1.0 = 0x3F80)
    bf8 ones;
    #pragma unroll
    for (int i = 0; i < 8; ++i) ones[i] = (short)0x3F80;

    // prologue: issue chunk0, load Q frags under its latency, stage, issue 1
    load_chunk(0, kA0r, kA1r, vA0r, vA1r);

    // persistent Q B-frags: lane n=q=lane&15, k=d=quad*8+e (+32 per step)
    bf8 qf[4][2];
    #pragma unroll
    for (int nq = 0; nq < 4; ++nq)
        #pragma unroll
        for (int st = 0; st < 2; ++st)
            qf[nq][st] = *(const bf8*)(qg + (rbase + qw + nq * 16 + m) * HS + st * 32 + quad * 8);

    write_chunk(0, kA0r, kA1r, vA0r, vA1r);   // one-time prologue drain
    load_chunk(1, kB0r, kB1r, vB0r, vB1r);
    __syncthreads();

    auto compute_g = [&](int p, int g) {
        bf8 kA0 = *(const bf8*)(&kl[p][(g * 32 + m) * 72 + quad * 8]);
        bf8 kA1 = *(const bf8*)(&kl[p][(g * 32 + m) * 72 + 32 + quad * 8]);
        bf8 kB0 = *(const bf8*)(&kl[p][(g * 32 + 16 + m) * 72 + quad * 8]);
        bf8 kB1 = *(const bf8*)(&kl[p][(g * 32 + 16 + m) * 72 + 32 + quad * 8]);

        bf8 vf[4];
        #pragma unroll
        for (int dt = 0; dt < 4; ++dt) {
            const int row = dt * 16 + m;
            const int key = (m & 7) ^ (2 * dt + (m >> 3));
            const int chunk = (g * 4 + quad) ^ key;
            vf[dt] = *(const bf8*)(&vl[p][row * 64 + chunk * 8]);
        }

        #pragma unroll
        for (int nq = 0; nq < 4; ++nq) {
            f4 sa = {0.f, 0.f, 0.f, 0.f}, sb = {0.f, 0.f, 0.f, 0.f};
            sa = __builtin_amdgcn_mfma_f32_16x16x32_bf16(kA0, qf[nq][0], sa, 0, 0, 0);
            sa = __builtin_amdgcn_mfma_f32_16x16x32_bf16(kA1, qf[nq][1], sa, 0, 0, 0);
            sb = __builtin_amdgcn_mfma_f32_16x16x32_bf16(kB0, qf[nq][0], sb, 0, 0, 0);
            sb = __builtin_amdgcn_mfma_f32_16x16x32_bf16(kB1, qf[nq][1], sb, 0, 0, 0);
            float e0 = EXP2F(sa[0]), e1 = EXP2F(sa[1]), e2 = EXP2F(sa[2]), e3 = EXP2F(sa[3]);
            float e4 = EXP2F(sb[0]), e5 = EXP2F(sb[1]), e6 = EXP2F(sb[2]), e7 = EXP2F(sb[3]);
            uint4 pu;
            pu.x = pk2(e0, e1); pu.y = pk2(e2, e3);
            pu.z = pk2(e4, e5); pu.w = pk2(e6, e7);
            bf8 pf = __builtin_bit_cast(bf8, pu);
            dacc[nq] = __builtin_amdgcn_mfma_f32_16x16x32_bf16(ones, pf, dacc[nq], 0, 0, 0);
            #pragma unroll
            for (int dt = 0; dt < 4; ++dt)
                o[nq][dt] = __builtin_amdgcn_mfma_f32_16x16x32_bf16(vf[dt], pf, o[nq][dt], 0, 0, 0);
        }
    };

    const int NCH = SEQ / 4 / 64;   // 16 chunks of 64 keys
    for (int cc = 0; cc < NCH; cc += 2) {
        {   // c = cc (even), p = 0: load chunk c+2 -> A, write chunk c+1 (from B) mid-chunk
            const int c = cc;
            if (c + 2 < NCH) load_chunk(c + 2, kA0r, kA1r, vA0r, vA1r);
            __builtin_amdgcn_s_setprio(1);
            compute_g(0, 0);
            __builtin_amdgcn_s_setprio(0);
            if (c + 1 < NCH) write_chunk(1, kB0r, kB1r, vB0r, vB1r);
            __builtin_amdgcn_s_setprio(1);
            compute_g(0, 1);
            __builtin_amdgcn_s_setprio(0);
            if (c + 1 < NCH) __syncthreads();
        }
        {   // c = cc+1 (odd), p = 1: load chunk c+2 -> B, write chunk c+1 (from A) mid-chunk
            const int c = cc + 1;
            if (c + 2 < NCH) load_chunk(c + 2, kB0r, kB1r, vB0r, vB1r);
            __builtin_amdgcn_s_setprio(1);
            compute_g(1, 0);
            __builtin_amdgcn_s_setprio(0);
            if (c + 1 < NCH) write_chunk(0, kA0r, kA1r, vA0r, vA1r);
            __builtin_amdgcn_s_setprio(1);
            compute_g(1, 1);
            __builtin_amdgcn_s_setprio(0);
            if (c + 1 < NCH) __syncthreads();
        }
    }

    // epilogue: O^T frag row=d=dt*16+quad*4+r, col=q=lane&15. Partial sums out.
    // dacc rows are all identical (ones-product), so every lane already holds
    // the full per-split den for its column q — no cross-lane reduce needed.
    #pragma unroll
    for (int nq = 0; nq < 4; ++nq) {
        const int orow = rbase + qw + nq * 16 + m;
        if (quad == 0) denp[orow] = dacc[nq][0];
        #pragma unroll
        for (int dt = 0; dt < 4; ++dt)
            *(f4*)(nump + orow * HS + dt * 16 + quad * 4) = o[nq][dt];
    }
}

// ---------------------------------------------------------------------------
// Kernel 3: combine the four key-splits: out = sum(num_i)/sum(den_i).
// ---------------------------------------------------------------------------
__global__ __launch_bounds__(256) void reduce_kernel(
    float* __restrict__ out, const float* __restrict__ num1,
    const float* __restrict__ num2, const float* __restrict__ num3,
    const float* __restrict__ den0, const float* __restrict__ den1,
    const float* __restrict__ den2, const float* __restrict__ den3)
{
    const int gid = blockIdx.x * 256 + threadIdx.x;
    const int base = gid * 4;
    const int r = base >> 6;
    f4 n0 = *(const f4*)(out + base);
    f4 n1 = *(const f4*)(num1 + base);
    f4 n2 = *(const f4*)(num2 + base);
    f4 n3 = *(const f4*)(num3 + base);
    const float rs = 1.0f / ((den0[r] + den1[r]) + (den2[r] + den3[r]));
    f4 res;
    #pragma unroll
    for (int i = 0; i < 4; ++i) res[i] = ((n0[i] + n1[i]) + (n2[i] + n3[i])) * rs;
    *(f4*)(out + base) = res;
}

extern "C" void kernel_launch(void* const* d_in, const int* in_sizes, int n_in,
                              void* d_out, int out_size, void* d_ws, size_t ws_size,
                              hipStream_t stream) {
    const float* ix = (const float*)d_in[0];
    const float* Wk = (const float*)d_in[1];
    const float* Wq = (const float*)d_in[2];
    const float* Wv = (const float*)d_in[3];
    float* out = (float*)d_out;

    const size_t NQKV = (size_t)NBATCH * SEQ * HS;      // 2,097,152 elements
    short* qg = (short*)d_ws;
    short* kg = qg + NQKV;
    short* vg = kg + NQKV;
    short* wt3 = vg + NQKV;                             // 24*192*32 = 147456 shorts
    char*  fbase = (char*)(wt3 + 24 * 192 * 32);        // 16B-aligned
    float* num1 = (float*)fbase;
    float* num2 = num1 + NQKV;
    float* num3 = num2 + NQKV;
    float* den0 = num3 + NQKV;
    float* den1 = den0 + (size_t)NBATCH * SEQ;
    float* den2 = den1 + (size_t)NBATCH * SEQ;
    float* den3 = den2 + (size_t)NBATCH * SEQ;

    wconv_kernel<<<(3 * D_DIM * HS) / 256, 256, 0, stream>>>(Wk, Wq, Wv, wt3);
    proj_kernel<<<(NBATCH * SEQ) / 32, 256, 0, stream>>>(ix, wt3, qg, kg, vg);
    attn_kernel<<<512, 256, 0, stream>>>(qg, kg, vg, out, num1, num2, num3,
                                         den0, den1, den2, den3);
    reduce_kernel<<<(int)(NQKV / (256 * 4)), 256, 0, stream>>>(
        out, num1, num2, num3, den0, den1, den2, den3);
}